// Round 13
// baseline (274.916 us; speedup 1.0000x reference)
//
#include <hip/hip_runtime.h>

#define NN 100000
#define DD 128
#define CC 40
#define BSH 9                      // bucket = dst >> 9
#define BSZ 512                    // nodes per bucket
#define NBK ((NN + BSZ - 1) / BSZ) // 196 buckets
#define CAPT 10240                 // tmp slots per bucket (mean 8163, sigma 90)
#define CAPP (CAPT + 7 * BSZ)      // padded adj slots per bucket (pad-to-8)
#define CS1 ((NN + 1) * 64)        // chunk stride (ushorts) for xh/h1 (+dummy)
#define CSM (NN * 64)              // chunk stride (ushorts) for mean

typedef unsigned int  uint;
typedef unsigned short ushort;

typedef __attribute__((ext_vector_type(8))) short  s16x8;   // 8 bf16 (4 VGPRs)
typedef __attribute__((ext_vector_type(4))) float  f32x4;
typedef __attribute__((ext_vector_type(4))) uint   u32x4;

// bf16 helpers (bit-level, round-to-nearest-even)
__device__ __forceinline__ float blo(uint u) { return __uint_as_float(u << 16); }
__device__ __forceinline__ float bhi(uint u) { return __uint_as_float(u & 0xFFFF0000u); }
__device__ __forceinline__ uint  f2b(float f) {
    uint u = __float_as_uint(f);
    return (u + 0x7FFFu + ((u >> 16) & 1u)) >> 16;
}
__device__ __forceinline__ uint pack2(float lo, float hi) { return f2b(lo) | (f2b(hi) << 16); }

// ---------------------------------------------------------------------------
// x (f32, row-major) -> xh (bf16, chunk-major [2][N+1][64 ushorts]);
// zeros dummy row NN of xh and h1.  One 16B segment per thread.
__global__ __launch_bounds__(256)
void k_cvt(const float* __restrict__ x, ushort* __restrict__ xh,
           ushort* __restrict__ h1, int n8) {
    int i = blockIdx.x * 256 + threadIdx.x;
    if (i < 16) {
        int chunk = i >> 3, w8 = (i & 7) * 8;
        u32x4 z = {0, 0, 0, 0};
        *reinterpret_cast<u32x4*>(xh + (size_t)chunk * CS1 + (size_t)NN * 64 + w8) = z;
        *reinterpret_cast<u32x4*>(h1 + (size_t)chunk * CS1 + (size_t)NN * 64 + w8) = z;
    }
    if (i >= n8) return;
    int r = i >> 4, seg = i & 15;
    const float* xp = x + (size_t)r * DD + seg * 8;
    float4 a = *reinterpret_cast<const float4*>(xp);
    float4 b = *reinterpret_cast<const float4*>(xp + 4);
    u32x4 o;
    o.x = pack2(a.x, a.y); o.y = pack2(a.z, a.w);
    o.z = pack2(b.x, b.y); o.w = pack2(b.z, b.w);
    int chunk = seg >> 3, w8 = (seg & 7) * 8;
    *reinterpret_cast<u32x4*>(xh + (size_t)chunk * CS1 + (size_t)r * 64 + w8) = o;
}

// ---------------------------------------------------------------------------
// pack weights into bf16 MFMA B-operand fragments.
__global__ __launch_bounds__(256)
void k_prepw(const float* __restrict__ Wl1, const float* __restrict__ Wr1,
             const float* __restrict__ Wl2, const float* __restrict__ Wr2,
             const float* __restrict__ Wout,
             uint* __restrict__ pB1, uint* __restrict__ pB2,
             uint* __restrict__ pBout) {
    int t = blockIdx.x * 256 + threadIdx.x;   // 0..8959
    if (t < 8192) {
        int layer = t >> 12;
        int r = t & 4095;
        int kb = r >> 9, nt = (r >> 6) & 7, l = r & 63;
        int n  = nt * 16 + (l & 15);
        int k0 = kb * 32 + ((l >> 4) << 3);       // chunk never straddles 128
        const float* W = (k0 < 128) ? (layer ? Wl2 : Wl1) : (layer ? Wr2 : Wr1);
        int kk = k0 & 127;
        float4 wa = *reinterpret_cast<const float4*>(W + n * DD + kk);
        float4 wb = *reinterpret_cast<const float4*>(W + n * DD + kk + 4);
        uint4 o;
        o.x = pack2(wa.x, wa.y); o.y = pack2(wa.z, wa.w);
        o.z = pack2(wb.x, wb.y); o.w = pack2(wb.z, wb.w);
        uint* pB = layer ? pB2 : pB1;
        *reinterpret_cast<uint4*>(pB + (size_t)r * 4) = o;
    } else if (t < 8960) {
        int r = t - 8192;                          // 0..767
        int kb = r / 192, rem = r % 192;
        int nt = rem >> 6, l = rem & 63;
        int n  = nt * 16 + (l & 15);
        int k0 = kb * 32 + ((l >> 4) << 3);
        uint4 o = {0, 0, 0, 0};
        if (n < CC) {
            float4 wa = *reinterpret_cast<const float4*>(Wout + n * DD + k0);
            float4 wb = *reinterpret_cast<const float4*>(Wout + n * DD + k0 + 4);
            o.x = pack2(wa.x, wa.y); o.y = pack2(wa.z, wa.w);
            o.z = pack2(wb.x, wb.y); o.w = pack2(wb.z, wb.w);
        }
        *reinterpret_cast<uint4*>(pBout + (size_t)r * 4) = o;
    }
}

// ---------------------------------------------------------------------------
// partition edges into fixed-capacity bucket regions (block-exclusive runs)
__global__ __launch_bounds__(256)
void k_partition(const int* __restrict__ src, const int* __restrict__ dst,
                 int* __restrict__ bcur, uint* __restrict__ tmp, int E) {
    __shared__ int h[NBK];
    __shared__ int cur[NBK];
    int chunk = (E + gridDim.x - 1) / gridDim.x;
    int lo = blockIdx.x * chunk;
    int hi = min(lo + chunk, E);
    for (int i = threadIdx.x; i < NBK; i += 256) h[i] = 0;
    __syncthreads();
    for (int i = lo + threadIdx.x; i < hi; i += 256)
        atomicAdd(&h[dst[i] >> BSH], 1);
    __syncthreads();
    for (int i = threadIdx.x; i < NBK; i += 256) {
        int c = h[i];
        cur[i] = c ? atomicAdd(&bcur[i], c) : 0;
    }
    __syncthreads();
    for (int i = lo + threadIdx.x; i < hi; i += 256) {
        int d = dst[i];
        int bkt = d >> BSH;
        int rel = atomicAdd(&cur[bkt], 1);
        if (rel < CAPT)
            tmp[(size_t)bkt * CAPT + rel] =
                ((uint)(d & (BSZ - 1)) << 17) | (uint)src[i];
    }
}

// per-bucket: LDS hist + pad-to-8 scan -> rowinfo{start,cnt}; scatter; dummies
__global__ __launch_bounds__(256)
void k_bucket(const uint* __restrict__ tmp, const int* __restrict__ bcnt,
              int2* __restrict__ rowinfo, int* __restrict__ adj) {
    __shared__ int cnt[BSZ];
    __shared__ int cur[BSZ];
    __shared__ int ps[256];
    int b = blockIdx.x, t = threadIdx.x;
    int count = min(bcnt[b], CAPT);
    const uint* tb = tmp + (size_t)b * CAPT;
    int bbP = b * CAPP;
    cnt[t] = 0; cnt[t + 256] = 0;
    __syncthreads();
    for (int i = t; i < count; i += 256)
        atomicAdd(&cnt[tb[i] >> 17], 1);
    __syncthreads();
    int c0 = cnt[2 * t], c1 = cnt[2 * t + 1];
    int p0 = (c0 + 7) & ~7, p1 = (c1 + 7) & ~7;
    ps[t] = p0 + p1;
    __syncthreads();
    for (int off = 1; off < 256; off <<= 1) {
        int add = (t >= off) ? ps[t - off] : 0;
        __syncthreads();
        ps[t] += add;
        __syncthreads();
    }
    int ex = ps[t] - (p0 + p1);
    cur[2 * t] = ex; cur[2 * t + 1] = ex + p0;
    int node0 = b * BSZ;
    if (node0 + 2 * t < NN)     rowinfo[node0 + 2 * t]     = make_int2(bbP + ex, c0);
    if (node0 + 2 * t + 1 < NN) rowinfo[node0 + 2 * t + 1] = make_int2(bbP + ex + p0, c1);
    __syncthreads();
    for (int i = t; i < count; i += 256) {
        uint e = tb[i];
        int pos = bbP + atomicAdd(&cur[e >> 17], 1);
        adj[pos] = (int)(e & 0x1FFFFu);
    }
    __syncthreads();
    // dummy slots -> zero row NN
    for (int q = c0; q < p0; ++q) adj[bbP + ex + q] = NN;
    int ex1 = ex + p0;
    for (int q = c1; q < p1; ++q) adj[bbP + ex1 + q] = NN;
}

// ---------------------------------------------------------------------------
// gather-aggregate, 2-chunk feature split: chunk = blockIdx&1 (XCD parity),
// one wave/node; 8 lanes/row x 16B -> 8 rows per dwordx4 gather.
__global__ __launch_bounds__(256)
void k_aggregate(const int2* __restrict__ rowinfo, const int* __restrict__ adj,
                 const ushort* __restrict__ xsrc, uint cs,
                 ushort* __restrict__ outm) {
    const int lane = threadIdx.x & 63;
    const int chunk = blockIdx.x & 1;
    const int w = (blockIdx.x >> 1) * 4 +
                  __builtin_amdgcn_readfirstlane(threadIdx.x >> 6);
    int2 ri = rowinfo[w];
    const int beg = __builtin_amdgcn_readfirstlane(ri.x);
    const int n   = __builtin_amdgcn_readfirstlane(ri.y);
    const int end = beg + ((n + 7) & ~7);
    const int rg = lane >> 3;                  // row group 0..7
    const uint co = (uint)((lane & 7) << 1);   // ushort8 offset: (lane&7)*8 ushorts
    const ushort* __restrict__ xc = xsrc + (size_t)chunk * cs;
    ushort* __restrict__ oc = outm + (size_t)chunk * CSM;

    float a0 = 0.f, a1 = 0.f, a2 = 0.f, a3 = 0.f;
    float a4 = 0.f, a5 = 0.f, a6 = 0.f, a7 = 0.f;

    #pragma unroll 2
    for (int j = beg; j < end; j += 8) {
        uint r = (uint)__builtin_nontemporal_load(adj + j + rg);
        u32x4 v = *reinterpret_cast<const u32x4*>(xc + r * 64u + co * 4u);
        a0 += blo(v.x); a1 += bhi(v.x); a2 += blo(v.y); a3 += bhi(v.y);
        a4 += blo(v.z); a5 += bhi(v.z); a6 += blo(v.w); a7 += bhi(v.w);
    }

    a0 += __shfl_xor(a0, 8);  a1 += __shfl_xor(a1, 8);
    a2 += __shfl_xor(a2, 8);  a3 += __shfl_xor(a3, 8);
    a4 += __shfl_xor(a4, 8);  a5 += __shfl_xor(a5, 8);
    a6 += __shfl_xor(a6, 8);  a7 += __shfl_xor(a7, 8);
    a0 += __shfl_xor(a0, 16); a1 += __shfl_xor(a1, 16);
    a2 += __shfl_xor(a2, 16); a3 += __shfl_xor(a3, 16);
    a4 += __shfl_xor(a4, 16); a5 += __shfl_xor(a5, 16);
    a6 += __shfl_xor(a6, 16); a7 += __shfl_xor(a7, 16);
    a0 += __shfl_xor(a0, 32); a1 += __shfl_xor(a1, 32);
    a2 += __shfl_xor(a2, 32); a3 += __shfl_xor(a3, 32);
    a4 += __shfl_xor(a4, 32); a5 += __shfl_xor(a5, 32);
    a6 += __shfl_xor(a6, 32); a7 += __shfl_xor(a7, 32);
    if (lane < 8) {
        float inv = 1.0f / fmaxf((float)n, 1.0f);
        u32x4 o;
        o.x = pack2(a0 * inv, a1 * inv);
        o.y = pack2(a2 * inv, a3 * inv);
        o.z = pack2(a4 * inv, a5 * inv);
        o.w = pack2(a6 * inv, a7 * inv);
        *reinterpret_cast<u32x4*>(oc + (uint)w * 64u + co * 4u) = o;
    }
}

// ---------------------------------------------------------------------------
// MFMA fused SAGE linear: h = relu([mean|xin] @ packedW + bias)
// chunk-major inputs.  HEAD=false: h -> LDS -> chunk-major bf16 store.
// HEAD=true:  h -> LDS, classifier head (h @ Wout^T + bout) via MFMA -> f32.
template <bool HEAD>
__global__ __launch_bounds__(256)
void k_linear_t(const ushort* __restrict__ mean, const ushort* __restrict__ xin,
                const uint* __restrict__ pB, const float* __restrict__ bias,
                ushort* __restrict__ outh,
                const uint* __restrict__ pBout, const float* __restrict__ bout,
                float* __restrict__ outf)
{
    __shared__ u32x4 sB[4096];   // 64 KB: [kb][nt][lane] 16B frags
    const int tid = threadIdx.x;
    const u32x4* pBv = reinterpret_cast<const u32x4*>(pB);
    #pragma unroll
    for (int i = 0; i < 16; ++i)
        sB[tid + i * 256] = pBv[tid + i * 256];

    const int w = tid >> 6, l = tid & 63;
    const int fq = l >> 4, fr = l & 15;
    const int rbase = blockIdx.x * 128 + w * 32;   // wave-exclusive 32 rows

    f32x4 acc[2][8] = {};
    __syncthreads();

    #pragma unroll
    for (int kb = 0; kb < 8; ++kb) {
        const ushort* In = (kb < 4) ? mean : xin;
        const uint cs    = (kb < 4) ? (uint)CSM : (uint)CS1;
        const int ko = (kb & 3) * 32 + fq * 8;      // bf16 index 0..127
        const ushort* pa = In + (size_t)(ko >> 6) * cs + (ko & 63);
        s16x8 a0 = __builtin_bit_cast(s16x8,
            *reinterpret_cast<const u32x4*>(pa + (size_t)(rbase + fr) * 64));
        s16x8 a1 = __builtin_bit_cast(s16x8,
            *reinterpret_cast<const u32x4*>(pa + (size_t)(rbase + 16 + fr) * 64));
        #pragma unroll
        for (int nt = 0; nt < 8; ++nt) {
            s16x8 b = __builtin_bit_cast(s16x8, sB[(kb * 8 + nt) * 64 + l]);
            acc[0][nt] = __builtin_amdgcn_mfma_f32_16x16x32_bf16(a0, b, acc[0][nt], 0, 0, 0);
            acc[1][nt] = __builtin_amdgcn_mfma_f32_16x16x32_bf16(a1, b, acc[1][nt], 0, 0, 0);
        }
    }

    __syncthreads();                     // all sB reads done; reuse as sH
    ushort* sH = reinterpret_cast<ushort*>(sB);
    const int LDH = 136;                 // +8 ushort pad (16B) per row
    #pragma unroll
    for (int nt = 0; nt < 8; ++nt) {
        float bn = bias[nt * 16 + fr];
        #pragma unroll
        for (int m = 0; m < 2; ++m) {
            #pragma unroll
            for (int reg = 0; reg < 4; ++reg) {
                int lrow = w * 32 + m * 16 + fq * 4 + reg;
                float o = fmaxf(acc[m][nt][reg] + bn, 0.0f);
                sH[lrow * LDH + nt * 16 + fr] = (ushort)f2b(o);
            }
        }
    }
    __syncthreads();

    if constexpr (!HEAD) {
        // chunk-major bf16 store: 128 rows x 16 segs of 16B = 2048 chunks
        #pragma unroll
        for (int k2 = 0; k2 < 8; ++k2) {
            int idx = k2 * 256 + tid;
            int row = idx >> 4, seg = idx & 15;
            int gr = blockIdx.x * 128 + row;
            if (gr < NN) {
                u32x4 v = *reinterpret_cast<const u32x4*>(sH + row * LDH + seg * 8);
                *reinterpret_cast<u32x4*>(outh + (size_t)(seg >> 3) * CS1 +
                                          (size_t)gr * 64 + (seg & 7) * 8) = v;
            }
        }
    } else {
        f32x4 oa[2][3] = {};
        #pragma unroll
        for (int kb2 = 0; kb2 < 4; ++kb2) {
            s16x8 a0 = *reinterpret_cast<const s16x8*>(
                sH + (w * 32 + fr) * LDH + kb2 * 32 + fq * 8);
            s16x8 a1 = *reinterpret_cast<const s16x8*>(
                sH + (w * 32 + 16 + fr) * LDH + kb2 * 32 + fq * 8);
            #pragma unroll
            for (int nt2 = 0; nt2 < 3; ++nt2) {
                s16x8 b = __builtin_bit_cast(s16x8,
                    *reinterpret_cast<const u32x4*>(
                        pBout + (size_t)((kb2 * 3 + nt2) * 64 + l) * 4));
                oa[0][nt2] = __builtin_amdgcn_mfma_f32_16x16x32_bf16(a0, b, oa[0][nt2], 0, 0, 0);
                oa[1][nt2] = __builtin_amdgcn_mfma_f32_16x16x32_bf16(a1, b, oa[1][nt2], 0, 0, 0);
            }
        }
        #pragma unroll
        for (int nt2 = 0; nt2 < 3; ++nt2) {
            int col = nt2 * 16 + fr;
            if (col < CC) {
                float bn = bout[col];
                #pragma unroll
                for (int m = 0; m < 2; ++m) {
                    #pragma unroll
                    for (int reg = 0; reg < 4; ++reg) {
                        int r = rbase + m * 16 + fq * 4 + reg;
                        if (r < NN)
                            outf[(size_t)r * CC + col] = oa[m][nt2][reg] + bn;
                    }
                }
            }
        }
    }
}

// ---------------------------------------------------------------------------
extern "C" void kernel_launch(void* const* d_in, const int* in_sizes, int n_in,
                              void* d_out, int out_size, void* d_ws, size_t ws_size,
                              hipStream_t stream)
{
    const float* x    = (const float*)d_in[0];
    const int*   ei   = (const int*)d_in[1];
    const float* Wl1  = (const float*)d_in[2];
    const float* bl1  = (const float*)d_in[3];
    const float* Wr1  = (const float*)d_in[4];
    const float* Wl2  = (const float*)d_in[5];
    const float* bl2  = (const float*)d_in[6];
    const float* Wr2  = (const float*)d_in[7];
    const float* Wout = (const float*)d_in[8];
    const float* bout = (const float*)d_in[9];
    float* out = (float*)d_out;

    const int E = in_sizes[1] / 2;
    const int* srcI = ei;        // edge_index[0]
    const int* dstI = ei + E;    // edge_index[1]

    // workspace layout (chunk-major activations):
    // xh [2*CS1] | m [2*CSM] | h1 [2*CS1] (ushorts) | rowinfo int2[N] |
    // adj [NBK*CAPP] | tmp [NBK*CAPT] | bcur [NBK] | pB1 | pB2 | pBout
    ushort* xh = (ushort*)d_ws;
    ushort* m  = xh + (size_t)2 * CS1;
    ushort* h1 = m + (size_t)2 * CSM;
    int2* rowinfo = (int2*)(h1 + (size_t)2 * CS1);
    int* adj  = (int*)(rowinfo + NN);
    uint* tmp = (uint*)(adj + (size_t)NBK * CAPP);
    int* bcur = (int*)(tmp + (size_t)NBK * CAPT);
    uintptr_t pb = ((uintptr_t)(bcur + NBK) + 15) & ~(uintptr_t)15;
    uint* pB1   = (uint*)pb;
    uint* pB2   = pB1 + 16384;
    uint* pBout = pB2 + 16384;

    dim3 b256(256);
    const int aggBlocks = (NN / 4) * 2;      // node-quads x 2 chunks
    const int linBlocks = (NN + 127) / 128;
    const int n8 = NN * DD / 8;

    // ---- convert x to bf16 chunk-major (+ dummy rows), pack weights, CSR
    k_cvt<<<(n8 + 255) / 256, b256, 0, stream>>>(x, xh, h1, n8);
    k_prepw<<<35, b256, 0, stream>>>(Wl1, Wr1, Wl2, Wr2, Wout, pB1, pB2, pBout);
    (void)hipMemsetAsync(bcur, 0, NBK * sizeof(int), stream);
    k_partition<<<256, b256, 0, stream>>>(srcI, dstI, bcur, tmp, E);
    k_bucket<<<NBK, b256, 0, stream>>>(tmp, bcur, rowinfo, adj);

    // ---- layer 1
    k_aggregate<<<aggBlocks, b256, 0, stream>>>(rowinfo, adj, xh, (uint)CS1, m);
    k_linear_t<false><<<linBlocks, b256, 0, stream>>>(m, xh, pB1, bl1, h1,
                                                      nullptr, nullptr, nullptr);

    // ---- layer 2 + fused classifier head
    k_aggregate<<<aggBlocks, b256, 0, stream>>>(rowinfo, adj, h1, (uint)CS1, m);
    k_linear_t<true><<<linBlocks, b256, 0, stream>>>(m, h1, pB2, bl2, nullptr,
                                                     pBout, bout, out);
}

// Round 14
// 217.581 us; speedup vs baseline: 1.2635x; 1.2635x over previous
//
#include <hip/hip_runtime.h>

#define NN 100000
#define DD 128
#define CC 40
#define BSH 9                      // bucket = dst >> 9
#define BSZ 512                    // nodes per bucket
#define NBK ((NN + BSZ - 1) / BSZ) // 196 buckets
#define CAPT 10240                 // tmp slots per bucket (mean 8163, sigma 90)
#define CAPP (CAPT + 7 * BSZ)      // padded adj slots per bucket (pad-to-8)
#define CVTB 6250                  // blocks doing x->bf16 (NN*DD/8/256)

typedef unsigned int  uint;
typedef unsigned short ushort;

typedef __attribute__((ext_vector_type(8))) short  s16x8;   // 8 bf16 (4 VGPRs)
typedef __attribute__((ext_vector_type(4))) float  f32x4;
typedef __attribute__((ext_vector_type(4))) uint   u32x4;

// bf16 helpers (bit-level, round-to-nearest-even)
__device__ __forceinline__ float blo(uint u) { return __uint_as_float(u << 16); }
__device__ __forceinline__ float bhi(uint u) { return __uint_as_float(u & 0xFFFF0000u); }
__device__ __forceinline__ uint  f2b(float f) {
    uint u = __float_as_uint(f);
    return (u + 0x7FFFu + ((u >> 16) & 1u)) >> 16;
}
__device__ __forceinline__ uint pack2(float lo, float hi) { return f2b(lo) | (f2b(hi) << 16); }

// ---------------------------------------------------------------------------
// merged pre-pass: blocks [0,CVTB): x f32 -> xh bf16 (+ zero dummy rows);
// blocks [CVTB, CVTB+35): pack weights into MFMA B-frags + zero bcur.
__global__ __launch_bounds__(256)
void k_pre(const float* __restrict__ x, uint* __restrict__ xh,
           uint* __restrict__ h1,
           const float* __restrict__ Wl1, const float* __restrict__ Wr1,
           const float* __restrict__ Wl2, const float* __restrict__ Wr2,
           const float* __restrict__ Wout,
           uint* __restrict__ pB1, uint* __restrict__ pB2,
           uint* __restrict__ pBout, int* __restrict__ bcur) {
    if (blockIdx.x < CVTB) {
        int i = blockIdx.x * 256 + threadIdx.x;
        if (i < 16) {
            u32x4 z = {0, 0, 0, 0};
            reinterpret_cast<u32x4*>(xh + (size_t)NN * 64)[i] = z;
            reinterpret_cast<u32x4*>(h1 + (size_t)NN * 64)[i] = z;
        }
        float4 a = reinterpret_cast<const float4*>(x)[(size_t)i * 2];
        float4 b = reinterpret_cast<const float4*>(x)[(size_t)i * 2 + 1];
        uint4 o;
        o.x = pack2(a.x, a.y); o.y = pack2(a.z, a.w);
        o.z = pack2(b.x, b.y); o.w = pack2(b.z, b.w);
        reinterpret_cast<uint4*>(xh)[i] = o;
        return;
    }
    int t = (blockIdx.x - CVTB) * 256 + threadIdx.x;   // 0..8959
    if (t < NBK) bcur[t] = 0;
    if (t < 8192) {
        int layer = t >> 12;
        int r = t & 4095;
        int kb = r >> 9, nt = (r >> 6) & 7, l = r & 63;
        int n  = nt * 16 + (l & 15);
        int k0 = kb * 32 + ((l >> 4) << 3);       // chunk never straddles 128
        const float* W = (k0 < 128) ? (layer ? Wl2 : Wl1) : (layer ? Wr2 : Wr1);
        int kk = k0 & 127;
        float4 wa = *reinterpret_cast<const float4*>(W + n * DD + kk);
        float4 wb = *reinterpret_cast<const float4*>(W + n * DD + kk + 4);
        uint4 o;
        o.x = pack2(wa.x, wa.y); o.y = pack2(wa.z, wa.w);
        o.z = pack2(wb.x, wb.y); o.w = pack2(wb.z, wb.w);
        uint* pB = layer ? pB2 : pB1;
        *reinterpret_cast<uint4*>(pB + (size_t)r * 4) = o;
    } else if (t < 8960) {
        int r = t - 8192;                          // 0..767
        int kb = r / 192, rem = r % 192;
        int nt = rem >> 6, l = rem & 63;
        int n  = nt * 16 + (l & 15);
        int k0 = kb * 32 + ((l >> 4) << 3);
        uint4 o = {0, 0, 0, 0};
        if (n < CC) {
            float4 wa = *reinterpret_cast<const float4*>(Wout + n * DD + k0);
            float4 wb = *reinterpret_cast<const float4*>(Wout + n * DD + k0 + 4);
            o.x = pack2(wa.x, wa.y); o.y = pack2(wa.z, wa.w);
            o.z = pack2(wb.x, wb.y); o.w = pack2(wb.z, wb.w);
        }
        *reinterpret_cast<uint4*>(pBout + (size_t)r * 4) = o;
    }
}

// ---------------------------------------------------------------------------
// partition edges into fixed-capacity bucket regions (block-exclusive runs)
__global__ __launch_bounds__(256)
void k_partition(const int* __restrict__ src, const int* __restrict__ dst,
                 int* __restrict__ bcur, uint* __restrict__ tmp, int E) {
    __shared__ int h[NBK];
    __shared__ int cur[NBK];
    int chunk = (E + gridDim.x - 1) / gridDim.x;
    int lo = blockIdx.x * chunk;
    int hi = min(lo + chunk, E);
    for (int i = threadIdx.x; i < NBK; i += 256) h[i] = 0;
    __syncthreads();
    for (int i = lo + threadIdx.x; i < hi; i += 256)
        atomicAdd(&h[dst[i] >> BSH], 1);
    __syncthreads();
    for (int i = threadIdx.x; i < NBK; i += 256) {
        int c = h[i];
        cur[i] = c ? atomicAdd(&bcur[i], c) : 0;
    }
    __syncthreads();
    for (int i = lo + threadIdx.x; i < hi; i += 256) {
        int d = dst[i];
        int bkt = d >> BSH;
        int rel = atomicAdd(&cur[bkt], 1);
        if (rel < CAPT)
            tmp[(size_t)bkt * CAPT + rel] =
                ((uint)(d & (BSZ - 1)) << 17) | (uint)src[i];
    }
}

// per-bucket: LDS hist + pad-to-8 scan -> rowinfo{start,cnt}; scatter; dummies
__global__ __launch_bounds__(256)
void k_bucket(const uint* __restrict__ tmp, const int* __restrict__ bcnt,
              int2* __restrict__ rowinfo, int* __restrict__ adj) {
    __shared__ int cnt[BSZ];
    __shared__ int cur[BSZ];
    __shared__ int ps[256];
    int b = blockIdx.x, t = threadIdx.x;
    int count = min(bcnt[b], CAPT);
    const uint* tb = tmp + (size_t)b * CAPT;
    int bbP = b * CAPP;
    cnt[t] = 0; cnt[t + 256] = 0;
    __syncthreads();
    for (int i = t; i < count; i += 256)
        atomicAdd(&cnt[tb[i] >> 17], 1);
    __syncthreads();
    int c0 = cnt[2 * t], c1 = cnt[2 * t + 1];
    int p0 = (c0 + 7) & ~7, p1 = (c1 + 7) & ~7;
    ps[t] = p0 + p1;
    __syncthreads();
    for (int off = 1; off < 256; off <<= 1) {
        int add = (t >= off) ? ps[t - off] : 0;
        __syncthreads();
        ps[t] += add;
        __syncthreads();
    }
    int ex = ps[t] - (p0 + p1);
    cur[2 * t] = ex; cur[2 * t + 1] = ex + p0;
    int node0 = b * BSZ;
    if (node0 + 2 * t < NN)     rowinfo[node0 + 2 * t]     = make_int2(bbP + ex, c0);
    if (node0 + 2 * t + 1 < NN) rowinfo[node0 + 2 * t + 1] = make_int2(bbP + ex + p0, c1);
    __syncthreads();
    for (int i = t; i < count; i += 256) {
        uint e = tb[i];
        int pos = bbP + atomicAdd(&cur[e >> 17], 1);
        adj[pos] = (int)(e & 0x1FFFFu);
    }
    __syncthreads();
    // dummy slots -> zero row NN
    for (int q = c0; q < p0; ++q) adj[bbP + ex + q] = NN;
    int ex1 = ex + p0;
    for (int q = c1; q < p1; ++q) adj[bbP + ex1 + q] = NN;
}

// ---------------------------------------------------------------------------
// gather-aggregate: one wave/node. Quad-split dwordx4 gathers: 16 lanes/row,
// 16B/lane -> 1KB / 4 rows per instruction; rows padded to x8 (no tail).
__global__ __launch_bounds__(256)
void k_aggregate(const int2* __restrict__ rowinfo, const int* __restrict__ adj,
                 const uint* __restrict__ xh, uint* __restrict__ outm) {
    const int lane = threadIdx.x & 63;
    const int w = blockIdx.x * 4 + __builtin_amdgcn_readfirstlane(threadIdx.x >> 6);
    int2 ri = rowinfo[w];
    const int beg = __builtin_amdgcn_readfirstlane(ri.x);
    const int n   = __builtin_amdgcn_readfirstlane(ri.y);
    const int end = beg + ((n + 7) & ~7);
    const uint co = (uint)((lane & 15) << 2);   // uint offset within row (16B)

    float a0 = 0.f, a1 = 0.f, a2 = 0.f, a3 = 0.f;
    float a4 = 0.f, a5 = 0.f, a6 = 0.f, a7 = 0.f;
    float b0 = 0.f, b1 = 0.f, b2 = 0.f, b3 = 0.f;
    float b4 = 0.f, b5 = 0.f, b6 = 0.f, b7 = 0.f;

    #pragma unroll 2
    for (int j = beg; j < end; j += 8) {
        u32x4 nA = __builtin_nontemporal_load(
            reinterpret_cast<const u32x4*>(adj + j));
        u32x4 nB = __builtin_nontemporal_load(
            reinterpret_cast<const u32x4*>(adj + j + 4));
        uint rA = (lane & 32) ? ((lane & 16) ? nA.w : nA.z)
                              : ((lane & 16) ? nA.y : nA.x);
        uint rB = (lane & 32) ? ((lane & 16) ? nB.w : nB.z)
                              : ((lane & 16) ? nB.y : nB.x);
        uint4 vA = *reinterpret_cast<const uint4*>(xh + (rA << 6) + co);
        uint4 vB = *reinterpret_cast<const uint4*>(xh + (rB << 6) + co);
        a0 += blo(vA.x); a1 += bhi(vA.x); a2 += blo(vA.y); a3 += bhi(vA.y);
        a4 += blo(vA.z); a5 += bhi(vA.z); a6 += blo(vA.w); a7 += bhi(vA.w);
        b0 += blo(vB.x); b1 += bhi(vB.x); b2 += blo(vB.y); b3 += bhi(vB.y);
        b4 += blo(vB.z); b5 += bhi(vB.z); b6 += blo(vB.w); b7 += bhi(vB.w);
    }

    float t0 = a0 + b0, t1 = a1 + b1, t2 = a2 + b2, t3 = a3 + b3;
    float t4 = a4 + b4, t5 = a5 + b5, t6 = a6 + b6, t7 = a7 + b7;
    t0 += __shfl_xor(t0, 16); t1 += __shfl_xor(t1, 16);
    t2 += __shfl_xor(t2, 16); t3 += __shfl_xor(t3, 16);
    t4 += __shfl_xor(t4, 16); t5 += __shfl_xor(t5, 16);
    t6 += __shfl_xor(t6, 16); t7 += __shfl_xor(t7, 16);
    t0 += __shfl_xor(t0, 32); t1 += __shfl_xor(t1, 32);
    t2 += __shfl_xor(t2, 32); t3 += __shfl_xor(t3, 32);
    t4 += __shfl_xor(t4, 32); t5 += __shfl_xor(t5, 32);
    t6 += __shfl_xor(t6, 32); t7 += __shfl_xor(t7, 32);
    if (lane < 16) {
        float inv = 1.0f / fmaxf((float)n, 1.0f);
        uint4 o;
        o.x = pack2(t0 * inv, t1 * inv);
        o.y = pack2(t2 * inv, t3 * inv);
        o.z = pack2(t4 * inv, t5 * inv);
        o.w = pack2(t6 * inv, t7 * inv);
        *reinterpret_cast<uint4*>(outm + (uint)(w * 64) + co) = o;
    }
}

// ---------------------------------------------------------------------------
// MFMA fused SAGE linear: h = relu([mean|xin] @ packedW + bias)
// HEAD=false: h -> LDS -> coalesced bf16 store.
// HEAD=true:  h -> LDS, classifier head (h @ Wout^T + bout) via MFMA -> f32.
template <bool HEAD>
__global__ __launch_bounds__(256)
void k_linear_t(const ushort* __restrict__ mean, const ushort* __restrict__ xin,
                const uint* __restrict__ pB, const float* __restrict__ bias,
                ushort* __restrict__ outh,
                const uint* __restrict__ pBout, const float* __restrict__ bout,
                float* __restrict__ outf)
{
    __shared__ u32x4 sB[4096];   // 64 KB: [kb][nt][lane] 16B frags
    const int tid = threadIdx.x;
    const u32x4* pBv = reinterpret_cast<const u32x4*>(pB);
    #pragma unroll
    for (int i = 0; i < 16; ++i)
        sB[tid + i * 256] = pBv[tid + i * 256];

    const int w = tid >> 6, l = tid & 63;
    const int fq = l >> 4, fr = l & 15;
    const int rbase = blockIdx.x * 128 + w * 32;   // wave-exclusive 32 rows

    f32x4 acc[2][8] = {};
    __syncthreads();

    #pragma unroll
    for (int kb = 0; kb < 8; ++kb) {
        const ushort* In = (kb < 4) ? mean : xin;
        const int ko = (kb & 3) * 32 + fq * 8;
        s16x8 a0 = __builtin_bit_cast(s16x8,
            *reinterpret_cast<const u32x4*>(In + (size_t)(rbase + fr) * DD + ko));
        s16x8 a1 = __builtin_bit_cast(s16x8,
            *reinterpret_cast<const u32x4*>(In + (size_t)(rbase + 16 + fr) * DD + ko));
        #pragma unroll
        for (int nt = 0; nt < 8; ++nt) {
            s16x8 b = __builtin_bit_cast(s16x8, sB[(kb * 8 + nt) * 64 + l]);
            acc[0][nt] = __builtin_amdgcn_mfma_f32_16x16x32_bf16(a0, b, acc[0][nt], 0, 0, 0);
            acc[1][nt] = __builtin_amdgcn_mfma_f32_16x16x32_bf16(a1, b, acc[1][nt], 0, 0, 0);
        }
    }

    __syncthreads();                     // all sB reads done; reuse as sH
    ushort* sH = reinterpret_cast<ushort*>(sB);
    const int LDH = 136;                 // +8 ushort pad (16B) per row
    #pragma unroll
    for (int nt = 0; nt < 8; ++nt) {
        float bn = bias[nt * 16 + fr];
        #pragma unroll
        for (int m = 0; m < 2; ++m) {
            #pragma unroll
            for (int reg = 0; reg < 4; ++reg) {
                int lrow = w * 32 + m * 16 + fq * 4 + reg;
                float o = fmaxf(acc[m][nt][reg] + bn, 0.0f);
                sH[lrow * LDH + nt * 16 + fr] = (ushort)f2b(o);
            }
        }
    }
    __syncthreads();

    if constexpr (!HEAD) {
        // coalesced bf16 store: 128 rows x 16 chunks of 16B = 2048 chunks
        #pragma unroll
        for (int k2 = 0; k2 < 8; ++k2) {
            int idx = k2 * 256 + tid;
            int row = idx >> 4, seg = idx & 15;
            int gr = blockIdx.x * 128 + row;
            if (gr < NN) {
                u32x4 v = *reinterpret_cast<const u32x4*>(sH + row * LDH + seg * 8);
                *reinterpret_cast<u32x4*>(outh + (size_t)gr * DD + seg * 8) = v;
            }
        }
    } else {
        f32x4 oa[2][3] = {};
        #pragma unroll
        for (int kb2 = 0; kb2 < 4; ++kb2) {
            s16x8 a0 = *reinterpret_cast<const s16x8*>(
                sH + (w * 32 + fr) * LDH + kb2 * 32 + fq * 8);
            s16x8 a1 = *reinterpret_cast<const s16x8*>(
                sH + (w * 32 + 16 + fr) * LDH + kb2 * 32 + fq * 8);
            #pragma unroll
            for (int nt2 = 0; nt2 < 3; ++nt2) {
                s16x8 b = __builtin_bit_cast(s16x8,
                    *reinterpret_cast<const u32x4*>(
                        pBout + (size_t)((kb2 * 3 + nt2) * 64 + l) * 4));
                oa[0][nt2] = __builtin_amdgcn_mfma_f32_16x16x32_bf16(a0, b, oa[0][nt2], 0, 0, 0);
                oa[1][nt2] = __builtin_amdgcn_mfma_f32_16x16x32_bf16(a1, b, oa[1][nt2], 0, 0, 0);
            }
        }
        #pragma unroll
        for (int nt2 = 0; nt2 < 3; ++nt2) {
            int col = nt2 * 16 + fr;
            if (col < CC) {
                float bn = bout[col];
                #pragma unroll
                for (int m = 0; m < 2; ++m) {
                    #pragma unroll
                    for (int reg = 0; reg < 4; ++reg) {
                        int r = rbase + m * 16 + fq * 4 + reg;
                        if (r < NN)
                            outf[(size_t)r * CC + col] = oa[m][nt2][reg] + bn;
                    }
                }
            }
        }
    }
}

// ---------------------------------------------------------------------------
extern "C" void kernel_launch(void* const* d_in, const int* in_sizes, int n_in,
                              void* d_out, int out_size, void* d_ws, size_t ws_size,
                              hipStream_t stream)
{
    const float* x    = (const float*)d_in[0];
    const int*   ei   = (const int*)d_in[1];
    const float* Wl1  = (const float*)d_in[2];
    const float* bl1  = (const float*)d_in[3];
    const float* Wr1  = (const float*)d_in[4];
    const float* Wl2  = (const float*)d_in[5];
    const float* bl2  = (const float*)d_in[6];
    const float* Wr2  = (const float*)d_in[7];
    const float* Wout = (const float*)d_in[8];
    const float* bout = (const float*)d_in[9];
    float* out = (float*)d_out;

    const int E = in_sizes[1] / 2;
    const int* srcI = ei;        // edge_index[0]
    const int* dstI = ei + E;    // edge_index[1]

    // workspace layout:
    // xh [(N+1)*64 uint] | m [N*64] | h1 [(N+1)*64] | rowinfo int2[N] |
    // adj [NBK*CAPP] | tmp [NBK*CAPT] | bcur [NBK] | pB1 | pB2 | pBout
    ushort* xh = (ushort*)d_ws;
    ushort* m  = xh + (size_t)(NN + 1) * DD;
    ushort* h1 = m + (size_t)NN * DD;
    int2* rowinfo = (int2*)(h1 + (size_t)(NN + 1) * DD);
    int* adj  = (int*)(rowinfo + NN);
    uint* tmp = (uint*)(adj + (size_t)NBK * CAPP);
    int* bcur = (int*)(tmp + (size_t)NBK * CAPT);
    uintptr_t pb = ((uintptr_t)(bcur + NBK) + 15) & ~(uintptr_t)15;
    uint* pB1   = (uint*)pb;
    uint* pB2   = pB1 + 16384;
    uint* pBout = pB2 + 16384;

    dim3 b256(256);
    const int aggBlocks = NN / 4;            // one wave per node
    const int linBlocks = (NN + 127) / 128;

    // ---- pre-pass: x->bf16 + dummy rows + weight packing + bcur zero
    k_pre<<<CVTB + 35, b256, 0, stream>>>(x, (uint*)xh, (uint*)h1,
                                          Wl1, Wr1, Wl2, Wr2, Wout,
                                          pB1, pB2, pBout, bcur);
    // ---- CSR build (bucket radix)
    k_partition<<<256, b256, 0, stream>>>(srcI, dstI, bcur, tmp, E);
    k_bucket<<<NBK, b256, 0, stream>>>(tmp, bcur, rowinfo, adj);

    // ---- layer 1
    k_aggregate<<<aggBlocks, b256, 0, stream>>>(rowinfo, adj, (const uint*)xh, (uint*)m);
    k_linear_t<false><<<linBlocks, b256, 0, stream>>>(m, xh, pB1, bl1, h1,
                                                      nullptr, nullptr, nullptr);

    // ---- layer 2 + fused classifier head
    k_aggregate<<<aggBlocks, b256, 0, stream>>>(rowinfo, adj, (const uint*)h1, (uint*)m);
    k_linear_t<true><<<linBlocks, b256, 0, stream>>>(m, h1, pB2, bl2, nullptr,
                                                     pBout, bout, out);
}